// Round 5
// baseline (40.816 us; speedup 1.0000x reference)
//
#include <hip/hip_runtime.h>
#include <hip/hip_bf16.h>
#include <math.h>

#define Tt 50
#define Dd 64
#define Bb 4096
#define Ss 64
#define ROWP 68  // padded LDS row (ushorts); 136 B rows, 8B-aligned

// d_ws layout: 32 u64 slots (stride 64 B) + ticket
#define WS_SLOTS 0
#define WS_TICKET 2048
#define WS_INIT_BYTES 2064

__device__ __forceinline__ float wsum(float v) {
#pragma unroll
  for (int m = 32; m >= 1; m >>= 1) v += __shfl_xor(v, m, 64);
  return v;
}
__device__ __forceinline__ float wmax(float v) {
#pragma unroll
  for (int m = 32; m >= 1; m >>= 1) v = fmaxf(v, __shfl_xor(v, m, 64));
  return v;
}
__device__ __forceinline__ float bf2f(unsigned short u) {
  return __uint_as_float(((unsigned)u) << 16);
}
__device__ __forceinline__ unsigned short f2bf(float f) {
  __hip_bfloat16 h = __float2bfloat16(f);  // RNE
  return __builtin_bit_cast(unsigned short, h);
}
// log(q), cancellation-free: log(id+2)-log(id+1) == log1p(1/(id+1))
__device__ __forceinline__ float logq_f(int id) {
  float idf = (float)id;
  float r = log1pf(1.0f / (idf + 1.0f));
  return logf(r * (1.0f / 12.2060776f));  // ln(200001)
}

__global__ __launch_bounds__(256, 4) void u2i_main(
    const float* __restrict__ item_table,
    const float* __restrict__ pos_table,
    const float* __restrict__ att_W,
    const float* __restrict__ att_b,
    const float* __restrict__ prelu_alpha,
    const float* __restrict__ zero_bias,
    const int* __restrict__ items_id,
    const int* __restrict__ position_id,
    const int* __restrict__ target_id,
    const int* __restrict__ keys_length,
    const int* __restrict__ sampled_ids,
    unsigned char* __restrict__ ws,
    float* __restrict__ out_vec)  // [0..4095]=output, [4096]=loss
{
  __shared__ unsigned short itemsB[4][Tt][ROWP];  // 27200 B (wave-private)
  __shared__ unsigned short sampB[Ss][ROWP];      //  8704 B (block-shared)
  __shared__ float poss[52];
  __shared__ float ut1_lds[4][Dd];
  __shared__ long long red[4];

  const int tid = threadIdx.x;
  const int lane = tid & 63;
  const int w = tid >> 6;
  const int b = (blockIdx.x << 2) | w;

  int idreg = 0, pidreg = 0;
  if (lane < Tt) {
    idreg = items_id[b * Tt + lane];
    pidreg = position_id[b * Tt + lane];
  }
  const int kl = keys_length[b];
  const int sub = lane >> 4;  // 0..3
  const int dg = lane & 15;   // 0..15
  const int d0g = dg << 2;

  // ---- everything address-known is issued up-front ----
  const int tgt = target_id[b];
  const int result = __shfl(idreg, kl - 1, 64);
  const int sid = sampled_ids[lane];
  float4 tv4 = *(const float4*)&item_table[(size_t)tgt * Dd + d0g];
  float4 tw4 = *(const float4*)&item_table[(size_t)result * Dd + d0g];
  const float zb_r = zero_bias[result];
  const float zb_s = zero_bias[sid];

  // ---- block-cooperative staging (cheap) : sampB + poss, then ONE barrier ----
#pragma unroll
  for (int k = 0; k < 4; ++k) {
    int s = (tid >> 4) + 16 * k;
    float4 x = *(const float4*)&item_table[(size_t)sampled_ids[s] * Dd + d0g];
    ushort4 o;
    o.x = f2bf(x.x); o.y = f2bf(x.y); o.z = f2bf(x.z); o.w = f2bf(x.w);
    *(ushort4*)&sampB[s][d0g] = o;
  }
  {
    float4 wp4 = *(const float4*)&att_W[Dd + d0g];
#pragma unroll
    for (int j = 0; j < 4; ++j) {
      int rel = 4 * j + sub;
      int p = 13 * w + rel;
      bool v = (rel < 13) && (p < Tt);
      float part = 0.0f;
      if (v) {
        float4 x = *(const float4*)&pos_table[p * Dd + d0g];
        part = x.x * wp4.x + x.y * wp4.y + x.z * wp4.z + x.w * wp4.w;
      }
#pragma unroll
      for (int mm = 1; mm <= 8; mm <<= 1) part += __shfl_xor(part, mm, 64);
      if (v && dg == 0) poss[p] = part;
    }
  }
  __syncthreads();  // the ONLY inter-wave barrier (covers sampB + poss)

  // ---- stage this wave's 50 item rows (wave-private, uncoupled) ----
#pragma unroll
  for (int c = 0; c < 13; ++c) {
    int t = 4 * c + sub;
    bool v = (t < Tt);
    int iid = __shfl(idreg, v ? t : 0, 64);
    if (v) {
      float4 x = *(const float4*)&item_table[(size_t)iid * Dd + d0g];
      ushort4 o;
      o.x = f2bf(x.x); o.y = f2bf(x.y); o.z = f2bf(x.z); o.w = f2bf(x.w);
      *(ushort4*)&itemsB[w][t][d0g] = o;
    }
  }

  // ---- phase 2: lane = t -> score, softmax (wave-local) ----
  const int trow = (lane < Tt) ? lane : (Tt - 1);
  const ushort4* rowp = (const ushort4*)&itemsB[w][trow][0];
  float a0 = 0, a1 = 0, a2 = 0, a3 = 0;
#pragma unroll
  for (int q = 0; q < 16; ++q) {
    ushort4 u = rowp[q];
    a0 += bf2f(u.x) * att_W[4 * q + 0];
    a1 += bf2f(u.y) * att_W[4 * q + 1];
    a2 += bf2f(u.z) * att_W[4 * q + 2];
    a3 += bf2f(u.w) * att_W[4 * q + 3];
  }
  float sc = tanhf((a0 + a1) + (a2 + a3) + poss[pidreg] + att_b[0]);
  float scv = (lane < kl) ? sc : -INFINITY;
  float m = wmax(scv);
  float e = (lane < kl) ? expf(sc - m) : 0.0f;
  float denom = wsum(e);
  float en = e / denom;  // normalized weight, lives in lane t
  unsigned long long mask = __ballot(lane < Tt - 1 && idreg != 0);

  // ---- phase 3: lane = (t-chunk, dg) -> pooling, output, true logit ----
  const int tbase = sub * 13;
  float4 sp4 = make_float4(0, 0, 0, 0), u14 = make_float4(0, 0, 0, 0);
#pragma unroll
  for (int i = 0; i < 13; ++i) {
    if (sub < 3 || i < 11) {
      const int t = tbase + i;
      float wt = __shfl(en, t, 64);  // broadcast from lane t
      ushort4 u = *(const ushort4*)&itemsB[w][t][d0g];
      float i0 = bf2f(u.x), i1 = bf2f(u.y), i2 = bf2f(u.z), i3 = bf2f(u.w);
      sp4.x += wt * i0; sp4.y += wt * i1;
      sp4.z += wt * i2; sp4.w += wt * i3;
      float wm = ((mask >> t) & 1ull) ? wt : 0.0f;
      u14.x += wm * i0; u14.y += wm * i1;
      u14.z += wm * i2; u14.w += wm * i3;
    }
  }
#pragma unroll
  for (int mm = 16; mm <= 32; mm <<= 1) {
    sp4.x += __shfl_xor(sp4.x, mm, 64); sp4.y += __shfl_xor(sp4.y, mm, 64);
    sp4.z += __shfl_xor(sp4.z, mm, 64); sp4.w += __shfl_xor(sp4.w, mm, 64);
    u14.x += __shfl_xor(u14.x, mm, 64); u14.y += __shfl_xor(u14.y, mm, 64);
    u14.z += __shfl_xor(u14.z, mm, 64); u14.w += __shfl_xor(u14.w, mm, 64);
  }

  float4 al = *(const float4*)&prelu_alpha[d0g];
  float4 sp;
  sp.x = sp4.x > 0.0f ? sp4.x : al.x * sp4.x;
  sp.y = sp4.y > 0.0f ? sp4.y : al.y * sp4.y;
  sp.z = sp4.z > 0.0f ? sp4.z : al.z * sp4.z;
  sp.w = sp4.w > 0.0f ? sp4.w : al.w * sp4.w;
  float op = sp.x * tv4.x + sp.y * tv4.y + sp.z * tv4.z + sp.w * tv4.w;
  float tp = u14.x * tw4.x + u14.y * tw4.y + u14.z * tw4.z + u14.w * tw4.w;
#pragma unroll
  for (int mm = 1; mm <= 8; mm <<= 1) {
    op += __shfl_xor(op, mm, 64);
    tp += __shfl_xor(tp, mm, 64);
  }
  if (lane == 0) out_vec[b] = op;
  float tl = tp + zb_r - logq_f(result);
  if (lane < 16) *(float4*)&ut1_lds[w][d0g] = u14;

  // ---- phase 4: lane = s -> sampled logits + loss ----
  const ushort4* srow = (const ushort4*)&sampB[lane][0];
  const float4* up = (const float4*)&ut1_lds[w][0];
  float acc = 0.0f;
#pragma unroll
  for (int q = 0; q < 16; ++q) {
    ushort4 u = srow[q];
    float4 uv = up[q];  // uniform -> broadcast
    acc += bf2f(u.x) * uv.x + bf2f(u.y) * uv.y + bf2f(u.z) * uv.z +
           bf2f(u.w) * uv.w;
  }
  float sl = acc + zb_s - logq_f(sid);
  if (sid == result) sl -= 1e9f;
  float mx = fmaxf(tl, wmax(sl));
  float se = wsum(expf(sl - mx)) + expf(tl - mx);
  float loss_b = (mx + logf(se)) - tl;
  if (lane == 0) red[w] = (long long)rintf(loss_b * 16777216.0f);

  __syncthreads();  // end-of-kernel: waves arrive nearly together
  if (tid == 0) {
    long long tot = red[0] + red[1] + red[2] + red[3];
    unsigned long long* slot =
        (unsigned long long*)(ws + WS_SLOTS) + (size_t)(blockIdx.x & 31) * 8;
    __hip_atomic_fetch_add(slot, (unsigned long long)tot, __ATOMIC_RELAXED,
                           __HIP_MEMORY_SCOPE_AGENT);
    unsigned int* ticket = (unsigned int*)(ws + WS_TICKET);
    unsigned int t = __hip_atomic_fetch_add(ticket, 1u, __ATOMIC_ACQ_REL,
                                            __HIP_MEMORY_SCOPE_AGENT);
    if (t == gridDim.x - 1) {  // all other blocks' adds are visible
      long long tot2 = 0;
#pragma unroll
      for (int i = 0; i < 32; ++i)
        tot2 += (long long)__hip_atomic_load(
            (unsigned long long*)(ws + WS_SLOTS) + (size_t)i * 8,
            __ATOMIC_RELAXED, __HIP_MEMORY_SCOPE_AGENT);
      out_vec[Bb] = (float)((double)tot2 * (1.0 / (16777216.0 * 4096.0)));
    }
  }
}

extern "C" void kernel_launch(void* const* d_in, const int* in_sizes, int n_in,
                              void* d_out, int out_size, void* d_ws, size_t ws_size,
                              hipStream_t stream) {
  const float* item_table  = (const float*)d_in[0];
  const float* pos_table   = (const float*)d_in[1];
  const float* att_W       = (const float*)d_in[2];
  const float* att_b       = (const float*)d_in[3];
  const float* prelu_alpha = (const float*)d_in[4];
  const float* zero_bias   = (const float*)d_in[5];
  const int* items_id      = (const int*)d_in[6];
  const int* position_id   = (const int*)d_in[7];
  const int* target_id     = (const int*)d_in[8];
  const int* keys_length   = (const int*)d_in[9];
  const int* sampled_ids   = (const int*)d_in[10];

  float* out = (float*)d_out;  // [0..4095]=output, [4096]=loss
  unsigned char* ws = (unsigned char*)d_ws;

  hipMemsetAsync(ws, 0, WS_INIT_BYTES, stream);  // zero slots + ticket (graph: memset node)
  u2i_main<<<Bb / 4, 256, 0, stream>>>(
      item_table, pos_table, att_W, att_b, prelu_alpha, zero_bias,
      items_id, position_id, target_id, keys_length, sampled_ids,
      ws, out);
}

// Round 6
// 27.594 us; speedup vs baseline: 1.4792x; 1.4792x over previous
//
#include <hip/hip_runtime.h>
#include <hip/hip_bf16.h>
#include <math.h>

#define Tt 50
#define Dd 64
#define Bb 4096
#define Ss 64
#define ROWP 68  // padded LDS row (ushorts); 136 B rows, 8B-aligned

__device__ __forceinline__ float wsum(float v) {
#pragma unroll
  for (int m = 32; m >= 1; m >>= 1) v += __shfl_xor(v, m, 64);
  return v;
}
__device__ __forceinline__ float wmax(float v) {
#pragma unroll
  for (int m = 32; m >= 1; m >>= 1) v = fmaxf(v, __shfl_xor(v, m, 64));
  return v;
}
__device__ __forceinline__ float bf2f(unsigned short u) {
  return __uint_as_float(((unsigned)u) << 16);
}
__device__ __forceinline__ unsigned short f2bf(float f) {
  __hip_bfloat16 h = __float2bfloat16(f);  // RNE
  return __builtin_bit_cast(unsigned short, h);
}
// log(q), cancellation-free: log(id+2)-log(id+1) == log1p(1/(id+1))
__device__ __forceinline__ float logq_f(int id) {
  float idf = (float)id;
  float r = log1pf(1.0f / (idf + 1.0f));
  return logf(r * (1.0f / 12.2060776f));  // ln(200001)
}

__global__ __launch_bounds__(256, 4) void u2i_main(
    const float* __restrict__ item_table,
    const float* __restrict__ pos_table,
    const float* __restrict__ att_W,
    const float* __restrict__ att_b,
    const float* __restrict__ prelu_alpha,
    const float* __restrict__ zero_bias,
    const int* __restrict__ items_id,
    const int* __restrict__ position_id,
    const int* __restrict__ target_id,
    const int* __restrict__ keys_length,
    const int* __restrict__ sampled_ids,
    float* __restrict__ out_vec,   // [B]
    float* __restrict__ loss_ws)   // [B]
{
  __shared__ unsigned short itemsB[4][Tt][ROWP];  // 27200 B (wave-private)
  __shared__ unsigned short sampB[Ss][ROWP];      //  8704 B (block-shared)
  __shared__ float poss[52];
  __shared__ float ut1_lds[4][Dd];

  const int tid = threadIdx.x;
  const int lane = tid & 63;
  const int w = tid >> 6;
  const int b = (blockIdx.x << 2) | w;

  int idreg = 0, pidreg = 0;
  if (lane < Tt) {
    idreg = items_id[b * Tt + lane];
    pidreg = position_id[b * Tt + lane];
  }
  const int kl = keys_length[b];
  const int sub = lane >> 4;  // 0..3
  const int dg = lane & 15;   // 0..15
  const int d0g = dg << 2;

  // ---- address-known loads issued up-front (latency hidden under staging) ----
  const int tgt = target_id[b];
  const int result = __shfl(idreg, kl - 1, 64);
  const int sid = sampled_ids[lane];
  float4 tv4 = *(const float4*)&item_table[(size_t)tgt * Dd + d0g];
  float4 tw4 = *(const float4*)&item_table[(size_t)result * Dd + d0g];
  const float zb_r = zero_bias[result];
  const float zb_s = zero_bias[sid];

  // ---- block-cooperative staging (8 cheap loads): sampB + poss, ONE barrier ----
#pragma unroll
  for (int k = 0; k < 4; ++k) {
    int s = (tid >> 4) + 16 * k;
    float4 x = *(const float4*)&item_table[(size_t)sampled_ids[s] * Dd + d0g];
    ushort4 o;
    o.x = f2bf(x.x); o.y = f2bf(x.y); o.z = f2bf(x.z); o.w = f2bf(x.w);
    *(ushort4*)&sampB[s][d0g] = o;
  }
  {
    float4 wp4 = *(const float4*)&att_W[Dd + d0g];
#pragma unroll
    for (int j = 0; j < 4; ++j) {
      int rel = 4 * j + sub;
      int p = 13 * w + rel;
      bool v = (rel < 13) && (p < Tt);
      float part = 0.0f;
      if (v) {
        float4 x = *(const float4*)&pos_table[p * Dd + d0g];
        part = x.x * wp4.x + x.y * wp4.y + x.z * wp4.z + x.w * wp4.w;
      }
#pragma unroll
      for (int mm = 1; mm <= 8; mm <<= 1) part += __shfl_xor(part, mm, 64);
      if (v && dg == 0) poss[p] = part;
    }
  }
  __syncthreads();  // only drains the cheap staging; item gathers come after

  // ---- stage this wave's 50 item rows (wave-private, uncoupled) ----
#pragma unroll
  for (int c = 0; c < 13; ++c) {
    int t = 4 * c + sub;
    bool v = (t < Tt);
    int iid = __shfl(idreg, v ? t : 0, 64);
    if (v) {
      float4 x = *(const float4*)&item_table[(size_t)iid * Dd + d0g];
      ushort4 o;
      o.x = f2bf(x.x); o.y = f2bf(x.y); o.z = f2bf(x.z); o.w = f2bf(x.w);
      *(ushort4*)&itemsB[w][t][d0g] = o;
    }
  }

  // ---- phase 2: lane = t -> score, softmax (wave-local) ----
  const int trow = (lane < Tt) ? lane : (Tt - 1);
  const ushort4* rowp = (const ushort4*)&itemsB[w][trow][0];
  float a0 = 0, a1 = 0, a2 = 0, a3 = 0;
#pragma unroll
  for (int q = 0; q < 16; ++q) {
    ushort4 u = rowp[q];
    a0 += bf2f(u.x) * att_W[4 * q + 0];
    a1 += bf2f(u.y) * att_W[4 * q + 1];
    a2 += bf2f(u.z) * att_W[4 * q + 2];
    a3 += bf2f(u.w) * att_W[4 * q + 3];
  }
  float sc = tanhf((a0 + a1) + (a2 + a3) + poss[pidreg] + att_b[0]);
  float scv = (lane < kl) ? sc : -INFINITY;
  float m = wmax(scv);
  float e = (lane < kl) ? expf(sc - m) : 0.0f;
  float denom = wsum(e);
  float en = e / denom;  // normalized weight lives in lane t
  unsigned long long mask = __ballot(lane < Tt - 1 && idreg != 0);

  // ---- phase 3: lane = (t-chunk, dg) -> pooling, output, true logit ----
  const int tbase = sub * 13;
  float4 sp4 = make_float4(0, 0, 0, 0), u14 = make_float4(0, 0, 0, 0);
#pragma unroll
  for (int i = 0; i < 13; ++i) {
    if (sub < 3 || i < 11) {
      const int t = tbase + i;
      float wt = __shfl(en, t, 64);  // broadcast from lane t
      ushort4 u = *(const ushort4*)&itemsB[w][t][d0g];
      float i0 = bf2f(u.x), i1 = bf2f(u.y), i2 = bf2f(u.z), i3 = bf2f(u.w);
      sp4.x += wt * i0; sp4.y += wt * i1;
      sp4.z += wt * i2; sp4.w += wt * i3;
      float wm = ((mask >> t) & 1ull) ? wt : 0.0f;
      u14.x += wm * i0; u14.y += wm * i1;
      u14.z += wm * i2; u14.w += wm * i3;
    }
  }
#pragma unroll
  for (int mm = 16; mm <= 32; mm <<= 1) {
    sp4.x += __shfl_xor(sp4.x, mm, 64); sp4.y += __shfl_xor(sp4.y, mm, 64);
    sp4.z += __shfl_xor(sp4.z, mm, 64); sp4.w += __shfl_xor(sp4.w, mm, 64);
    u14.x += __shfl_xor(u14.x, mm, 64); u14.y += __shfl_xor(u14.y, mm, 64);
    u14.z += __shfl_xor(u14.z, mm, 64); u14.w += __shfl_xor(u14.w, mm, 64);
  }

  float4 al = *(const float4*)&prelu_alpha[d0g];
  float4 sp;
  sp.x = sp4.x > 0.0f ? sp4.x : al.x * sp4.x;
  sp.y = sp4.y > 0.0f ? sp4.y : al.y * sp4.y;
  sp.z = sp4.z > 0.0f ? sp4.z : al.z * sp4.z;
  sp.w = sp4.w > 0.0f ? sp4.w : al.w * sp4.w;
  float op = sp.x * tv4.x + sp.y * tv4.y + sp.z * tv4.z + sp.w * tv4.w;
  float tp = u14.x * tw4.x + u14.y * tw4.y + u14.z * tw4.z + u14.w * tw4.w;
#pragma unroll
  for (int mm = 1; mm <= 8; mm <<= 1) {
    op += __shfl_xor(op, mm, 64);
    tp += __shfl_xor(tp, mm, 64);
  }
  if (lane == 0) out_vec[b] = op;
  float tl = tp + zb_r - logq_f(result);
  if (lane < 16) *(float4*)&ut1_lds[w][d0g] = u14;

  // ---- phase 4: lane = s -> sampled logits + loss ----
  const ushort4* srow = (const ushort4*)&sampB[lane][0];
  const float4* up = (const float4*)&ut1_lds[w][0];
  float acc = 0.0f;
#pragma unroll
  for (int q = 0; q < 16; ++q) {
    ushort4 u = srow[q];
    float4 uv = up[q];  // uniform -> broadcast
    acc += bf2f(u.x) * uv.x + bf2f(u.y) * uv.y + bf2f(u.z) * uv.z +
           bf2f(u.w) * uv.w;
  }
  float sl = acc + zb_s - logq_f(sid);
  if (sid == result) sl -= 1e9f;
  float mx = fmaxf(tl, wmax(sl));
  float se = wsum(expf(sl - mx)) + expf(tl - mx);
  if (lane == 0) loss_ws[b] = (mx + logf(se)) - tl;
}

__global__ __launch_bounds__(256) void loss_reduce_kernel(
    const float* __restrict__ ws, float* __restrict__ out_loss) {
  __shared__ float red[4];
  float acc = 0.0f;
  for (int i = threadIdx.x; i < Bb; i += 256) acc += ws[i];
  acc = wsum(acc);
  if ((threadIdx.x & 63) == 0) red[threadIdx.x >> 6] = acc;
  __syncthreads();
  if (threadIdx.x == 0)
    out_loss[0] = (red[0] + red[1] + red[2] + red[3]) * (1.0f / (float)Bb);
}

extern "C" void kernel_launch(void* const* d_in, const int* in_sizes, int n_in,
                              void* d_out, int out_size, void* d_ws, size_t ws_size,
                              hipStream_t stream) {
  const float* item_table  = (const float*)d_in[0];
  const float* pos_table   = (const float*)d_in[1];
  const float* att_W       = (const float*)d_in[2];
  const float* att_b       = (const float*)d_in[3];
  const float* prelu_alpha = (const float*)d_in[4];
  const float* zero_bias   = (const float*)d_in[5];
  const int* items_id      = (const int*)d_in[6];
  const int* position_id   = (const int*)d_in[7];
  const int* target_id     = (const int*)d_in[8];
  const int* keys_length   = (const int*)d_in[9];
  const int* sampled_ids   = (const int*)d_in[10];

  float* out = (float*)d_out;     // [0..4095]=output, [4096]=loss
  float* loss_ws = (float*)d_ws;  // B floats

  u2i_main<<<Bb / 4, 256, 0, stream>>>(
      item_table, pos_table, att_W, att_b, prelu_alpha, zero_bias,
      items_id, position_id, target_id, keys_length, sampled_ids,
      out, loss_ws);
  loss_reduce_kernel<<<1, 256, 0, stream>>>(loss_ws, out + Bb);
}

// Round 7
// 25.858 us; speedup vs baseline: 1.5784x; 1.0671x over previous
//
#include <hip/hip_runtime.h>
#include <hip/hip_bf16.h>
#include <math.h>

#define Tt 50
#define Dd 64
#define Bb 4096
#define Ss 64
#define ROWP 68  // padded LDS row (ushorts); 136 B rows, 8B-aligned

__device__ __forceinline__ float wsum(float v) {
#pragma unroll
  for (int m = 32; m >= 1; m >>= 1) v += __shfl_xor(v, m, 64);
  return v;
}
__device__ __forceinline__ float wmax(float v) {
#pragma unroll
  for (int m = 32; m >= 1; m >>= 1) v = fmaxf(v, __shfl_xor(v, m, 64));
  return v;
}
__device__ __forceinline__ float bf2f(unsigned short u) {
  return __uint_as_float(((unsigned)u) << 16);
}
__device__ __forceinline__ unsigned short f2bf(float f) {
  __hip_bfloat16 h = __float2bfloat16(f);  // RNE
  return __builtin_bit_cast(unsigned short, h);
}
// log(q), cancellation-free: log(id+2)-log(id+1) == log1p(1/(id+1))
__device__ __forceinline__ float logq_f(int id) {
  float idf = (float)id;
  float r = log1pf(1.0f / (idf + 1.0f));
  return logf(r * (1.0f / 12.2060776f));  // ln(200001)
}

__global__ __launch_bounds__(256, 4) void u2i_main(
    const float* __restrict__ item_table,
    const float* __restrict__ pos_table,
    const float* __restrict__ att_W,
    const float* __restrict__ att_b,
    const float* __restrict__ prelu_alpha,
    const float* __restrict__ zero_bias,
    const int* __restrict__ items_id,
    const int* __restrict__ position_id,
    const int* __restrict__ target_id,
    const int* __restrict__ keys_length,
    const int* __restrict__ sampled_ids,
    float* __restrict__ out_vec,   // [B]
    float* __restrict__ loss_ws)   // [B]
{
  __shared__ unsigned short sampB[Ss][ROWP];  // 8704 B (block-shared)
  __shared__ float ut1_lds[4][Dd];            // 1024 B (wave-private rows)

  const int tid = threadIdx.x;
  const int lane = tid & 63;
  const int w = tid >> 6;
  const int b = (blockIdx.x << 2) | w;

  int idreg = 0, pidreg = 0;
  if (lane < Tt) {
    idreg = items_id[b * Tt + lane];
    pidreg = position_id[b * Tt + lane];
  }
  const int kl = keys_length[b];
  const int sub = lane >> 4;  // 0..3
  const int dg = lane & 15;   // 0..15
  const int d0g = dg << 2;

  // ---- block-cooperative sampled-table staging, then the ONLY barrier ----
#pragma unroll
  for (int k = 0; k < 4; ++k) {
    int s = (tid >> 4) + 16 * k;
    float4 x = *(const float4*)&item_table[(size_t)sampled_ids[s] * Dd + d0g];
    ushort4 o;
    o.x = f2bf(x.x); o.y = f2bf(x.y); o.z = f2bf(x.z); o.w = f2bf(x.w);
    *(ushort4*)&sampB[s][d0g] = o;
  }
  __syncthreads();

  // ---- address-known dependent loads issued early ----
  const int tgt = target_id[b];
  const int result = __shfl(idreg, kl - 1, 64);
  const int sid = sampled_ids[lane];
  float4 tv4 = *(const float4*)&item_table[(size_t)tgt * Dd + d0g];
  float4 tw4 = *(const float4*)&item_table[(size_t)result * Dd + d0g];
  const float zb_r = zero_bias[result];
  const float zb_s = zero_bias[sid];

  // ---- fused gather + score partial; items stay in registers (packed bf16) ----
  const float4 Wi4 = *(const float4*)&att_W[d0g];
  const float4 Wp4 = *(const float4*)&att_W[Dd + d0g];
  unsigned pk0[13], pk1[13];
  float v[13];
#pragma unroll
  for (int c = 0; c < 13; ++c) {
    const int t = 4 * c + sub;
    const int tt = (t < Tt) ? t : 0;  // t=50,51 -> dummy row, masked later
    int iid = __shfl(idreg, tt, 64);
    int pid = __shfl(pidreg, tt, 64);
    float4 x = *(const float4*)&item_table[(size_t)iid * Dd + d0g];
    float4 p = *(const float4*)&pos_table[pid * Dd + d0g];
    v[c] = x.x * Wi4.x + x.y * Wi4.y + x.z * Wi4.z + x.w * Wi4.w +
           p.x * Wp4.x + p.y * Wp4.y + p.z * Wp4.z + p.w * Wp4.w;
    pk0[c] = ((unsigned)f2bf(x.y) << 16) | f2bf(x.x);
    pk1[c] = ((unsigned)f2bf(x.w) << 16) | f2bf(x.z);
  }
  // 16-lane butterfly: score for t=4c+sub lands in all lanes of group sub
#pragma unroll
  for (int c = 0; c < 13; ++c) {
    float s = v[c];
    s += __shfl_xor(s, 1, 64); s += __shfl_xor(s, 2, 64);
    s += __shfl_xor(s, 4, 64); s += __shfl_xor(s, 8, 64);
    v[c] = s;
  }
  const float ab = att_b[0];
  float lmax = -INFINITY;
#pragma unroll
  for (int c = 0; c < 13; ++c) {
    const int t = 4 * c + sub;
    v[c] = tanhf(v[c] + ab);
    if (t < kl) lmax = fmaxf(lmax, v[c]);
  }
  lmax = fmaxf(lmax, __shfl_xor(lmax, 16, 64));
  lmax = fmaxf(lmax, __shfl_xor(lmax, 32, 64));
  float lsum = 0.0f;
#pragma unroll
  for (int c = 0; c < 13; ++c) {
    const int t = 4 * c + sub;
    float e = (t < kl) ? __expf(v[c] - lmax) : 0.0f;
    v[c] = e;
    lsum += e;
  }
  lsum += __shfl_xor(lsum, 16, 64);
  lsum += __shfl_xor(lsum, 32, 64);
  const float inv = 1.0f / lsum;
  const unsigned long long mask = __ballot(lane < Tt - 1 && idreg != 0);

  // ---- phase 3 from registers: pooling partials over t = 4c+sub ----
  float4 sp4 = make_float4(0, 0, 0, 0), u14 = make_float4(0, 0, 0, 0);
#pragma unroll
  for (int c = 0; c < 13; ++c) {
    const int t = 4 * c + sub;
    float wt = v[c] * inv;
    float wm = ((mask >> t) & 1ull) ? wt : 0.0f;
    float x0 = bf2f((unsigned short)pk0[c]);
    float x1 = bf2f((unsigned short)(pk0[c] >> 16));
    float x2 = bf2f((unsigned short)pk1[c]);
    float x3 = bf2f((unsigned short)(pk1[c] >> 16));
    sp4.x += wt * x0; sp4.y += wt * x1; sp4.z += wt * x2; sp4.w += wt * x3;
    u14.x += wm * x0; u14.y += wm * x1; u14.z += wm * x2; u14.w += wm * x3;
  }
#pragma unroll
  for (int mm = 16; mm <= 32; mm <<= 1) {
    sp4.x += __shfl_xor(sp4.x, mm, 64); sp4.y += __shfl_xor(sp4.y, mm, 64);
    sp4.z += __shfl_xor(sp4.z, mm, 64); sp4.w += __shfl_xor(sp4.w, mm, 64);
    u14.x += __shfl_xor(u14.x, mm, 64); u14.y += __shfl_xor(u14.y, mm, 64);
    u14.z += __shfl_xor(u14.z, mm, 64); u14.w += __shfl_xor(u14.w, mm, 64);
  }

  float4 al = *(const float4*)&prelu_alpha[d0g];
  float4 sp;
  sp.x = sp4.x > 0.0f ? sp4.x : al.x * sp4.x;
  sp.y = sp4.y > 0.0f ? sp4.y : al.y * sp4.y;
  sp.z = sp4.z > 0.0f ? sp4.z : al.z * sp4.z;
  sp.w = sp4.w > 0.0f ? sp4.w : al.w * sp4.w;
  float op = sp.x * tv4.x + sp.y * tv4.y + sp.z * tv4.z + sp.w * tv4.w;
  float tp = u14.x * tw4.x + u14.y * tw4.y + u14.z * tw4.z + u14.w * tw4.w;
#pragma unroll
  for (int mm = 1; mm <= 8; mm <<= 1) {
    op += __shfl_xor(op, mm, 64);
    tp += __shfl_xor(tp, mm, 64);
  }
  if (lane == 0) out_vec[b] = op;
  float tl = tp + zb_r - logq_f(result);
  if (lane < 16) *(float4*)&ut1_lds[w][d0g] = u14;

  // ---- phase 4: lane = s -> sampled logits + loss ----
  const ushort4* srow = (const ushort4*)&sampB[lane][0];
  const float4* up = (const float4*)&ut1_lds[w][0];
  float acc = 0.0f;
#pragma unroll
  for (int q = 0; q < 16; ++q) {
    ushort4 u = srow[q];
    float4 uv = up[q];  // uniform -> broadcast
    acc += bf2f(u.x) * uv.x + bf2f(u.y) * uv.y + bf2f(u.z) * uv.z +
           bf2f(u.w) * uv.w;
  }
  float sl = acc + zb_s - logq_f(sid);
  if (sid == result) sl -= 1e9f;
  float mx = fmaxf(tl, wmax(sl));
  float se = wsum(__expf(sl - mx)) + __expf(tl - mx);
  if (lane == 0) loss_ws[b] = (mx + logf(se)) - tl;
}

__global__ __launch_bounds__(256) void loss_reduce_kernel(
    const float* __restrict__ ws, float* __restrict__ out_loss) {
  __shared__ float red[4];
  float acc = 0.0f;
  for (int i = threadIdx.x; i < Bb; i += 256) acc += ws[i];
  acc = wsum(acc);
  if ((threadIdx.x & 63) == 0) red[threadIdx.x >> 6] = acc;
  __syncthreads();
  if (threadIdx.x == 0)
    out_loss[0] = (red[0] + red[1] + red[2] + red[3]) * (1.0f / (float)Bb);
}

extern "C" void kernel_launch(void* const* d_in, const int* in_sizes, int n_in,
                              void* d_out, int out_size, void* d_ws, size_t ws_size,
                              hipStream_t stream) {
  const float* item_table  = (const float*)d_in[0];
  const float* pos_table   = (const float*)d_in[1];
  const float* att_W       = (const float*)d_in[2];
  const float* att_b       = (const float*)d_in[3];
  const float* prelu_alpha = (const float*)d_in[4];
  const float* zero_bias   = (const float*)d_in[5];
  const int* items_id      = (const int*)d_in[6];
  const int* position_id   = (const int*)d_in[7];
  const int* target_id     = (const int*)d_in[8];
  const int* keys_length   = (const int*)d_in[9];
  const int* sampled_ids   = (const int*)d_in[10];

  float* out = (float*)d_out;     // [0..4095]=output, [4096]=loss
  float* loss_ws = (float*)d_ws;  // B floats

  u2i_main<<<Bb / 4, 256, 0, stream>>>(
      item_table, pos_table, att_W, att_b, prelu_alpha, zero_bias,
      items_id, position_id, target_id, keys_length, sampled_ids,
      out, loss_ws);
  loss_reduce_kernel<<<1, 256, 0, stream>>>(loss_ws, out + Bb);
}